// Round 3
// baseline (735.974 us; speedup 1.0000x reference)
//
#include <hip/hip_runtime.h>
#include <stddef.h>

#define TT 2048
#define NN 4096
#define LSEG 64
#define NSEG (TT / LSEG)   // 32
#define ATPB 1024
#define NPT 4
#define TPB 256
#define TPBB 128           // phase-B tile kernels
#define NOFIRE 0xFFFFFFFEu
#define LRROWS 256         // precomputed log-table rows (lives in ys tail)

// ---- log-table precompute: lr[t][n] = logf(ru[t][n]+1e-12f)-0.01f, t<LRROWS
__global__ __launch_bounds__(TPB) void plog_k(const float* __restrict__ ru,
                                              float* __restrict__ lr) {
  int idx = blockIdx.x * TPB + threadIdx.x;
  const float4 x = ((const float4*)ru)[idx];
  float4 y;
  y.x = logf(x.x + 1e-12f) - 0.01f;
  y.y = logf(x.y + 1e-12f) - 0.01f;
  y.z = logf(x.z + 1e-12f) - 0.01f;
  y.w = logf(x.w + 1e-12f) - 0.01f;
  ((float4*)lr)[idx] = y;
}

// ---------------- Phase A: whole network on ONE CU, zero communication ------
// 1024 threads x 4 contiguous neurons, all state in registers. Per step: one
// intra-block argmin (shfl-min + 1 LDS atomicMin/wave + 1 barrier). All loads
// float4; ys row stored as 3x dwordx4/thread. Arithmetic per neuron is
// op-for-op identical to the R1/R2-verified kernels.
__global__ __launch_bounds__(ATPB) void phaseA(
    const float* __restrict__ ts, const float* __restrict__ inp,
    const float* __restrict__ w, const float* __restrict__ v0,
    const float* __restrict__ i0, const float* __restrict__ mu,
    const float* __restrict__ s0u, const float* __restrict__ ru,
    const float* __restrict__ lr, const int* __restrict__ mx,
    float* __restrict__ ys, unsigned int* __restrict__ hdr)
{
#pragma clang fp contract(off)
  const int tid = threadIdx.x;
  const int nb = tid * NPT;
  const float dt = ts[1] - ts[0];
  const float mu1 = mu[0], mu2 = mu[1];
  const int maxs = mx[0];

  float v[NPT], ci[NPT], s[NPT], wv[NPT], inpc[NPT], lvc[NPT];
  bool aw[NPT];
  {
    const float4 a = *(const float4*)(v0 + nb);
    const float4 b = *(const float4*)(i0 + nb);
    const float4 c = *(const float4*)(s0u + nb);
    const float4 d = *(const float4*)(inp + nb);
    const float4 e = *(const float4*)(lr + nb);   // row 0 (< LRROWS)
    v[0]=a.x; v[1]=a.y; v[2]=a.z; v[3]=a.w;
    ci[0]=b.x; ci[1]=b.y; ci[2]=b.z; ci[3]=b.w;
    s[0]=logf(c.x+1e-12f)-0.01f; s[1]=logf(c.y+1e-12f)-0.01f;
    s[2]=logf(c.z+1e-12f)-0.01f; s[3]=logf(c.w+1e-12f)-0.01f;
    inpc[0]=d.x; inpc[1]=d.y; inpc[2]=d.z; inpc[3]=d.w;
    lvc[0]=e.x; lvc[1]=e.y; lvc[2]=e.z; lvc[3]=e.w;
  }
  bool logged = true;
#pragma unroll
  for (int k = 0; k < NPT; ++k) { wv[k] = 0.0f; aw[k] = false; }

  __shared__ unsigned int slot[3];
  if (tid < 3) slot[tid] = NOFIRE;
  __syncthreads();

  int nsp = 0, t_stop = TT;

  for (int t = 0; t < TT; ++t) {
    // 1. prefetch next row (consumed next iteration)
    float inpn[NPT], lvn[NPT];
    bool logged_n = false;
    if (t + 1 < TT) {
      const float4 x = *(const float4*)(inp + (size_t)(t + 1) * NN + nb);
      logged_n = (t + 1) < LRROWS;
      const float* lp = logged_n ? lr : ru;
      const float4 y = *(const float4*)(lp + (size_t)(t + 1) * NN + nb);
      inpn[0]=x.x; inpn[1]=x.y; inpn[2]=x.z; inpn[3]=x.w;
      lvn[0]=y.x; lvn[1]=y.y; lvn[2]=y.z; lvn[3]=y.w;
    } else {
#pragma unroll
      for (int k = 0; k < NPT; ++k) { inpn[k] = 0.0f; lvn[k] = 0.0f; }
    }

    // 2. sigmoid / s_n / ev / candidate min
    float sn[NPT]; bool ev[NPT];
    unsigned int m = NOFIRE;
#pragma unroll
    for (int k = 0; k < NPT; ++k) {
      float sig = 1.0f / (1.0f + expf(-v[k]));
      sn[k] = s[k] + dt * sig;
      ev[k] = sn[k] >= 0.0f;
      unsigned int c = ev[k] ? (unsigned int)(nb + k) : NOFIRE;
      m = m < c ? m : c;
    }
    const bool coupled = (nsp < maxs);   // uniform
    if (coupled) {
#pragma unroll
      for (int off = 32; off > 0; off >>= 1) {
        unsigned int o = (unsigned int)__shfl_down((int)m, off, 64);
        m = m < o ? m : o;
      }
      if ((tid & 63) == 0) atomicMin(&slot[t % 3], m);
    }

    // 3. resolve pending w add, store ys[t-1], drift (overlaps barrier)
    float fi[NPT];
#pragma unroll
    for (int k = 0; k < NPT; ++k) fi[k] = aw[k] ? (ci[k] + wv[k]) : ci[k];
    if (t > 0) {
      float4* o = (float4*)(ys + ((size_t)(t - 1) * NN + nb) * 3);
      o[0] = make_float4(v[0], fi[0], s[0], v[1]);
      o[1] = make_float4(fi[1], s[1], v[2], fi[2]);
      o[2] = make_float4(s[2], v[3], fi[3], s[3]);
    }
    float vn[NPT], in_[NPT];
#pragma unroll
    for (int k = 0; k < NPT; ++k) {
      vn[k]  = v[k] + dt * (mu1 * (fi[k] - v[k]) + mu1 * inpc[k]);
      in_[k] = fi[k] + dt * (-mu2 * fi[k]);
    }

    // 4. barrier + read global argmin; rotate-reset slot read at t-1
    unsigned int gm = NOFIRE;
    if (coupled) {
      __syncthreads();
      gm = slot[t % 3];
      if (tid == 0) slot[(t + 2) % 3] = NOFIRE;
    }

    // 5. apply transition
    const bool fire = coupled && (gm < (unsigned int)NN);
#pragma unroll
    for (int k = 0; k < NPT; ++k) aw[k] = false;
    if (fire) {
      ++nsp;
      const float4 wr4 = *(const float4*)(w + (size_t)gm * NN + nb);
      wv[0]=wr4.x; wv[1]=wr4.y; wv[2]=wr4.z; wv[3]=wr4.w;   // consumed next iter
#pragma unroll
      for (int k = 0; k < NPT; ++k) {
        if (ev[k]) {
          v[k] = vn[k] - 1.0f;
          s[k] = logged ? lvc[k] : (logf(lvc[k] + 1e-12f) - 0.01f);
        } else { v[k] = vn[k]; s[k] = sn[k]; aw[k] = true; }
      }
    } else {
#pragma unroll
      for (int k = 0; k < NPT; ++k) { v[k] = vn[k]; s[k] = sn[k]; }
    }
#pragma unroll
    for (int k = 0; k < NPT; ++k) { ci[k] = in_[k]; inpc[k] = inpn[k]; lvc[k] = lvn[k]; }
    logged = logged_n;

    if (nsp >= maxs && ((t + 1) & (LSEG - 1)) == 0) { t_stop = t + 1; break; }
  }

  // flush final deferred store
  {
    float fi[NPT];
#pragma unroll
    for (int k = 0; k < NPT; ++k) fi[k] = aw[k] ? (ci[k] + wv[k]) : ci[k];
    float4* o = (float4*)(ys + ((size_t)(t_stop - 1) * NN + nb) * 3);
    o[0] = make_float4(v[0], fi[0], s[0], v[1]);
    o[1] = make_float4(fi[1], s[1], v[2], fi[2]);
    o[2] = make_float4(s[2], v[3], fi[3], s[3]);
  }
  if (tid == 0) hdr[0] = (unsigned int)t_stop;
}

// ---------------- Phase B: decoupled closed-form tail (float4 over n) -------
__global__ __launch_bounds__(TPBB) void p1_segc(
    const float* __restrict__ ts, const float* __restrict__ inp,
    const float* __restrict__ mu, const float* __restrict__ ys,
    const unsigned int* __restrict__ hdr, float* __restrict__ buf1)
{
  const unsigned int Kp = hdr[0];
  const unsigned int g0 = Kp / LSEG;
  const unsigned int g = blockIdx.x >> 3;
  if (g < g0) return;
  const int nb = ((int)(blockIdx.x & 7) * TPBB + threadIdx.x) * 4;
  const float dt = ts[1] - ts[0];
  const float mu1 = mu[0], mu2 = mu[1];
  const float a = 1.0f - dt * mu1, b = dt * mu1, r = 1.0f - dt * mu2;
  const float4* yb = (const float4*)(ys + ((size_t)(Kp - 1) * NN + nb) * 3);
  const float4 y0 = yb[0], y1 = yb[1], y2 = yb[2];
  const float pw = powf(r, (float)((int)(g * LSEG) - (int)Kp));
  float ij[4] = { y0.y * pw, y1.x * pw, y1.w * pw, y2.z * pw };
  float c[4] = {0.f, 0.f, 0.f, 0.f};
  const float* base = inp + (size_t)g * LSEG * NN + nb;
  for (int j = 0; j < LSEG; ++j) {
    const float4 x = *(const float4*)(base + (size_t)j * NN);
    c[0] = a * c[0] + b * (ij[0] + x.x); ij[0] *= r;
    c[1] = a * c[1] + b * (ij[1] + x.y); ij[1] *= r;
    c[2] = a * c[2] + b * (ij[2] + x.z); ij[2] *= r;
    c[3] = a * c[3] + b * (ij[3] + x.w); ij[3] *= r;
  }
  *(float4*)(buf1 + (size_t)g * NN + nb) = make_float4(c[0], c[1], c[2], c[3]);
}

__global__ __launch_bounds__(TPB) void p2_scanv(
    const float* __restrict__ ts, const float* __restrict__ mu,
    const float* __restrict__ ys, const unsigned int* __restrict__ hdr,
    float* __restrict__ buf1)
{
  const unsigned int Kp = hdr[0];
  const unsigned int g0 = Kp / LSEG;
  if (g0 >= NSEG) return;
  const int n = blockIdx.x * TPB + threadIdx.x;
  const float dt = ts[1] - ts[0];
  const float a = 1.0f - dt * mu[0];
  float aL = a;
  for (int k = 0; k < 6; ++k) aL *= aL;   // a^64
  float v = ys[((size_t)(Kp - 1) * NN + n) * 3];
  for (unsigned int g = g0; g < NSEG; ++g) {
    float cg = buf1[(size_t)g * NN + n];
    buf1[(size_t)g * NN + n] = v;
    v = aL * v + cg;
  }
}

__global__ __launch_bounds__(TPBB) void p3a_sigma(
    const float* __restrict__ ts, const float* __restrict__ inp,
    const float* __restrict__ mu, const unsigned int* __restrict__ hdr,
    const float* __restrict__ buf1, const float* __restrict__ ys,
    float* __restrict__ buf2)
{
  const unsigned int Kp = hdr[0];
  const unsigned int g0 = Kp / LSEG;
  const unsigned int g = blockIdx.x >> 3;
  if (g < g0) return;
  const int nb = ((int)(blockIdx.x & 7) * TPBB + threadIdx.x) * 4;
  const float dt = ts[1] - ts[0];
  const float mu1 = mu[0], mu2 = mu[1];
  const float r = 1.0f - dt * mu2;
  const float4 vb = *(const float4*)(buf1 + (size_t)g * NN + nb);
  float v[4] = { vb.x, vb.y, vb.z, vb.w };
  const float4* yb = (const float4*)(ys + ((size_t)(Kp - 1) * NN + nb) * 3);
  const float4 y0 = yb[0], y1 = yb[1], y2 = yb[2];
  const float pw = powf(r, (float)((int)(g * LSEG) - (int)Kp));
  float i[4] = { y0.y * pw, y1.x * pw, y1.w * pw, y2.z * pw };
  float sl[4] = {0.f, 0.f, 0.f, 0.f};
  const float* base = inp + (size_t)g * LSEG * NN + nb;
  for (int j = 0; j < LSEG; ++j) {
    const float4 x = *(const float4*)(base + (size_t)j * NN);
    float xx[4] = { x.x, x.y, x.z, x.w };
#pragma unroll
    for (int k = 0; k < 4; ++k) {
      float sig = 1.0f / (1.0f + expf(-v[k]));
      sl[k] = sl[k] + dt * sig;
      float vn = v[k] + dt * (mu1 * (i[k] - v[k]) + mu1 * xx[k]);
      float in_ = i[k] + dt * (-mu2 * i[k]);
      v[k] = vn; i[k] = in_;
    }
  }
  *(float4*)(buf2 + (size_t)g * NN + nb) = make_float4(sl[0], sl[1], sl[2], sl[3]);
}

__global__ __launch_bounds__(TPB) void p4_scans(
    const float* __restrict__ ys, const unsigned int* __restrict__ hdr,
    float* __restrict__ buf2)
{
  const unsigned int Kp = hdr[0];
  const unsigned int g0 = Kp / LSEG;
  if (g0 >= NSEG) return;
  const int n = blockIdx.x * TPB + threadIdx.x;
  float s = ys[((size_t)(Kp - 1) * NN + n) * 3 + 2];
  for (unsigned int g = g0; g < NSEG; ++g) {
    float t = buf2[(size_t)g * NN + n];
    buf2[(size_t)g * NN + n] = s;
    s += t;
  }
}

__global__ __launch_bounds__(TPBB) void p3b_write(
    const float* __restrict__ ts, const float* __restrict__ inp,
    const float* __restrict__ mu, const unsigned int* __restrict__ hdr,
    const float* __restrict__ buf1, const float* __restrict__ buf2,
    float* __restrict__ ys)
{
  const unsigned int Kp = hdr[0];
  const unsigned int g0 = Kp / LSEG;
  const unsigned int g = blockIdx.x >> 3;
  if (g < g0) return;
  const int nb = ((int)(blockIdx.x & 7) * TPBB + threadIdx.x) * 4;
  const float dt = ts[1] - ts[0];
  const float mu1 = mu[0], mu2 = mu[1];
  const float r = 1.0f - dt * mu2;
  const float4 vb = *(const float4*)(buf1 + (size_t)g * NN + nb);
  const float4 sb = *(const float4*)(buf2 + (size_t)g * NN + nb);
  float v[4] = { vb.x, vb.y, vb.z, vb.w };
  float s[4] = { sb.x, sb.y, sb.z, sb.w };
  const float4* yb = (const float4*)(ys + ((size_t)(Kp - 1) * NN + nb) * 3);
  const float4 y0 = yb[0], y1 = yb[1], y2 = yb[2];
  const float pw = powf(r, (float)((int)(g * LSEG) - (int)Kp));
  float i[4] = { y0.y * pw, y1.x * pw, y1.w * pw, y2.z * pw };
  const float* base = inp + (size_t)g * LSEG * NN + nb;
  for (int j = 0; j < LSEG; ++j) {
    const float4 x = *(const float4*)(base + (size_t)j * NN);
    float xx[4] = { x.x, x.y, x.z, x.w };
    float vn[4], in_[4];
#pragma unroll
    for (int k = 0; k < 4; ++k) {
      float sig = 1.0f / (1.0f + expf(-v[k]));
      s[k] = s[k] + dt * sig;
      vn[k] = v[k] + dt * (mu1 * (i[k] - v[k]) + mu1 * xx[k]);
      in_[k] = i[k] + dt * (-mu2 * i[k]);
    }
    float4* o = (float4*)(ys + (((size_t)g * LSEG + j) * NN + nb) * 3);
    o[0] = make_float4(vn[0], in_[0], s[0], vn[1]);
    o[1] = make_float4(in_[1], s[1], vn[2], in_[2]);
    o[2] = make_float4(s[2], vn[3], in_[3], s[3]);
#pragma unroll
    for (int k = 0; k < 4; ++k) { v[k] = vn[k]; i[k] = in_[k]; }
  }
}

extern "C" void kernel_launch(void* const* d_in, const int* in_sizes, int n_in,
                              void* d_out, int out_size, void* d_ws, size_t ws_size,
                              hipStream_t stream)
{
  (void)in_sizes; (void)n_in; (void)out_size; (void)ws_size;
  const float* ts  = (const float*)d_in[0];
  const float* inp = (const float*)d_in[1];
  const float* w   = (const float*)d_in[2];
  const float* v0  = (const float*)d_in[3];
  const float* i0  = (const float*)d_in[4];
  const float* mu  = (const float*)d_in[5];
  const float* s0u = (const float*)d_in[6];
  const float* ru  = (const float*)d_in[7];
  const int*   mx  = (const int*)d_in[8];
  float* ys = (float*)d_out;

  char* wsb = (char*)d_ws;
  unsigned int* hdr = (unsigned int*)wsb;                 // 64 B used
  float* buf1 = (float*)(wsb + 1024);                     // NSEG*NN*4 = 512 KB
  float* buf2 = buf1 + (size_t)NSEG * NN;                 // 512 KB

  // log-table lives in the TAIL of ys (last LRROWS*NN floats = 4 MB). That
  // region is only ever written afterwards by p3b (rows >= K'), which runs
  // after phaseA has finished consuming the table (phaseA reads it only for
  // t < LRROWS and writes row j at step j+1 >> LRROWS).
  float* lr = ys + (size_t)TT * NN * 3 - (size_t)LRROWS * NN;

  plog_k<<<LRROWS * NN / 4 / TPB, TPB, 0, stream>>>(ru, lr);
  phaseA<<<1, ATPB, 0, stream>>>(ts, inp, w, v0, i0, mu, s0u, ru, lr, mx, ys, hdr);
  p1_segc<<<NSEG * 8, TPBB, 0, stream>>>(ts, inp, mu, ys, hdr, buf1);
  p2_scanv<<<NN / TPB, TPB, 0, stream>>>(ts, mu, ys, hdr, buf1);
  p3a_sigma<<<NSEG * 8, TPBB, 0, stream>>>(ts, inp, mu, hdr, buf1, ys, buf2);
  p4_scans<<<NN / TPB, TPB, 0, stream>>>(ys, hdr, buf2);
  p3b_write<<<NSEG * 8, TPBB, 0, stream>>>(ts, inp, mu, hdr, buf1, buf2, ys);
}

// Round 4
// 651.722 us; speedup vs baseline: 1.1293x; 1.1293x over previous
//
#include <hip/hip_runtime.h>
#include <stddef.h>

#define TT 2048
#define NN 4096
#define LSEG 64
#define NSEG (TT / LSEG)   // 32
#define ATPB 1024
#define NPT 4
#define TPB 256
#define RTPB 64
#define CH 8
#define NOFIRE 0xFFFFFFFEu
#define LRROWS 256         // precomputed log-table rows (lives in ys tail)

// ---- log-table precompute: lr[t][n] = logf(ru[t][n]+1e-12f)-0.01f, t<LRROWS
__global__ __launch_bounds__(TPB) void plog_k(const float* __restrict__ ru,
                                              float* __restrict__ lr) {
#pragma clang fp contract(off)
  int idx = blockIdx.x * TPB + threadIdx.x;
  const float4 x = ((const float4*)ru)[idx];
  float4 y;
  y.x = logf(x.x + 1e-12f) - 0.01f;
  y.y = logf(x.y + 1e-12f) - 0.01f;
  y.z = logf(x.z + 1e-12f) - 0.01f;
  y.w = logf(x.w + 1e-12f) - 0.01f;
  ((float4*)lr)[idx] = y;
}

// ---------------- Phase A: decisions only, one CU --------------------------
// 1024 threads x 4 contiguous neurons, all state in registers. Writes ONLY the
// per-step event trace (gm or NOFIRE) + t_stop. No ys stores, no ru-row
// streaming (predicated lr gather at fire steps). Per-neuron arithmetic is
// op-for-op identical to the verified R1-R3 kernels.
__global__ __launch_bounds__(ATPB) void phaseA(
    const float* __restrict__ ts, const float* __restrict__ inp,
    const float* __restrict__ w, const float* __restrict__ v0,
    const float* __restrict__ i0, const float* __restrict__ mu,
    const float* __restrict__ s0u, const float* __restrict__ ru,
    const float* __restrict__ lr, const int* __restrict__ mx,
    unsigned int* __restrict__ trace, unsigned int* __restrict__ hdr)
{
#pragma clang fp contract(off)
  const int tid = threadIdx.x;
  const int nb = tid * NPT;
  const float dt = ts[1] - ts[0];
  const float mu1 = mu[0], mu2 = mu[1];
  const int maxs = mx[0];

  float v[NPT], ci[NPT], s[NPT], wv[NPT], inpc[NPT];
  bool aw[NPT];
  {
    const float4 a = *(const float4*)(v0 + nb);
    const float4 b = *(const float4*)(i0 + nb);
    const float4 c = *(const float4*)(s0u + nb);
    const float4 d = *(const float4*)(inp + nb);
    v[0]=a.x; v[1]=a.y; v[2]=a.z; v[3]=a.w;
    ci[0]=b.x; ci[1]=b.y; ci[2]=b.z; ci[3]=b.w;
    s[0]=logf(c.x+1e-12f)-0.01f; s[1]=logf(c.y+1e-12f)-0.01f;
    s[2]=logf(c.z+1e-12f)-0.01f; s[3]=logf(c.w+1e-12f)-0.01f;
    inpc[0]=d.x; inpc[1]=d.y; inpc[2]=d.z; inpc[3]=d.w;
  }
#pragma unroll
  for (int k = 0; k < NPT; ++k) { wv[k] = 0.0f; aw[k] = false; }

  __shared__ unsigned int slot[3];
  if (tid < 3) slot[tid] = NOFIRE;
  __syncthreads();

  int nsp = 0, t_stop = TT;
  const float4* pin = (const float4*)(inp + NN) + tid;   // row 1

  for (int t = 0; t < TT; ++t) {
    // prefetch inp row t+1 (consumed next iteration)
    float4 nx = make_float4(0.f, 0.f, 0.f, 0.f);
    if (t + 1 < TT) nx = *pin;
    pin += NN / 4;

    // sigmoid / s_n / ev / candidate min
    float sn[NPT]; bool ev[NPT];
    unsigned int m = NOFIRE;
#pragma unroll
    for (int k = 0; k < NPT; ++k) {
      float sig = 1.0f / (1.0f + expf(-v[k]));
      sn[k] = s[k] + dt * sig;
      ev[k] = sn[k] >= 0.0f;
      unsigned int c = ev[k] ? (unsigned int)(nb + k) : NOFIRE;
      m = m < c ? m : c;
    }
#pragma unroll
    for (int off = 32; off > 0; off >>= 1) {
      unsigned int o = (unsigned int)__shfl_down((int)m, off, 64);
      m = m < o ? m : o;
    }
    if ((tid & 63) == 0) atomicMin(&slot[t % 3], m);

    // resolve pending w add + drift (overlaps the barrier window)
    float fi[NPT], vn[NPT], in_[NPT];
#pragma unroll
    for (int k = 0; k < NPT; ++k) {
      fi[k] = aw[k] ? (ci[k] + wv[k]) : ci[k];
      vn[k] = v[k] + dt * (mu1 * (fi[k] - v[k]) + mu1 * inpc[k]);
      in_[k] = fi[k] + dt * (-mu2 * fi[k]);
    }

    __syncthreads();
    unsigned int gm = slot[t % 3];
    if (tid == 0) slot[(t + 2) % 3] = NOFIRE;

    const bool fire = (nsp < maxs) && (gm < (unsigned int)NN);
    if (tid == 0) trace[t] = fire ? gm : NOFIRE;

#pragma unroll
    for (int k = 0; k < NPT; ++k) aw[k] = false;
    if (fire) {
      ++nsp;
      const float4 w4 = *(const float4*)(w + (size_t)gm * NN + nb);
      wv[0]=w4.x; wv[1]=w4.y; wv[2]=w4.z; wv[3]=w4.w;   // consumed next iter
      if (t < LRROWS) {
#pragma unroll
        for (int k = 0; k < NPT; ++k)
          if (ev[k]) s[k] = lr[(size_t)t * NN + nb + k];   // sparse gather
      } else {
#pragma unroll
        for (int k = 0; k < NPT; ++k)
          if (ev[k]) s[k] = logf(ru[(size_t)t * NN + nb + k] + 1e-12f) - 0.01f;
      }
#pragma unroll
      for (int k = 0; k < NPT; ++k) {
        if (ev[k]) v[k] = vn[k] - 1.0f;
        else { v[k] = vn[k]; s[k] = sn[k]; aw[k] = true; }
      }
    } else {
#pragma unroll
      for (int k = 0; k < NPT; ++k) { v[k] = vn[k]; s[k] = sn[k]; }
    }
#pragma unroll
    for (int k = 0; k < NPT; ++k) ci[k] = in_[k];
    inpc[0]=nx.x; inpc[1]=nx.y; inpc[2]=nx.z; inpc[3]=nx.w;

    if (nsp >= maxs && ((t + 1) & (LSEG - 1)) == 0) { t_stop = t + 1; break; }
  }
  if (tid == 0) hdr[0] = (unsigned int)t_stop;
}

// ---------------- Replay: regenerate ys[0..t_stop) in parallel -------------
// One thread per neuron; trace in LDS; inp/lr/w prefetched one 8-step chunk
// ahead. Arithmetic identical to phaseA => bit-identical trajectories.
__global__ __launch_bounds__(RTPB) void replay_k(
    const float* __restrict__ ts, const float* __restrict__ inp,
    const float* __restrict__ w, const float* __restrict__ v0,
    const float* __restrict__ i0, const float* __restrict__ mu,
    const float* __restrict__ s0u, const float* __restrict__ ru,
    const float* __restrict__ lr, const unsigned int* __restrict__ trace,
    const unsigned int* __restrict__ hdr, float* __restrict__ ys)
{
#pragma clang fp contract(off)
  const int n = blockIdx.x * RTPB + threadIdx.x;
  const int tstop = (int)hdr[0];
  const float dt = ts[1] - ts[0];
  const float mu1 = mu[0], mu2 = mu[1];

  __shared__ unsigned int str[TT];
  for (int j = threadIdx.x; j < tstop; j += RTPB) str[j] = trace[j];
  __syncthreads();

  float v = v0[n];
  float ci = i0[n];
  float s = logf(s0u[n] + 1e-12f) - 0.01f;

  float inA[CH], lrA[CH], wA[CH], inB[CH], lrB[CH], wB[CH];
  const int nch = tstop / CH;

  // preload chunk 0
  {
    const float* lp = (0 < LRROWS) ? lr : ru;
#pragma unroll
    for (int j = 0; j < CH; ++j) {
      inA[j] = inp[(size_t)j * NN + n];
      lrA[j] = lp[(size_t)j * NN + n];
      unsigned int g = str[j];
      wA[j] = (g != NOFIRE) ? w[(size_t)g * NN + n] : 0.0f;
    }
  }

  for (int c = 0; c < nch; ++c) {
    if (c + 1 < nch) {
      const int t0 = (c + 1) * CH;
      const float* lp = (t0 < LRROWS) ? lr : ru;
#pragma unroll
      for (int j = 0; j < CH; ++j) {
        inB[j] = inp[(size_t)(t0 + j) * NN + n];
        lrB[j] = lp[(size_t)(t0 + j) * NN + n];
        unsigned int g = str[t0 + j];
        wB[j] = (g != NOFIRE) ? w[(size_t)g * NN + n] : 0.0f;
      }
    }
    const bool logged = (c * CH) < LRROWS;
#pragma unroll
    for (int j = 0; j < CH; ++j) {
      const int t = c * CH + j;
      float sig = 1.0f / (1.0f + expf(-v));
      float sn = s + dt * sig;
      bool ev = sn >= 0.0f;
      float vn = v + dt * (mu1 * (ci - v) + mu1 * inA[j]);
      float in_ = ci + dt * (-mu2 * ci);
      unsigned int g = str[t];
      if (g != NOFIRE) {
        if (ev) {
          v = vn - 1.0f;
          s = logged ? lrA[j] : (logf(lrA[j] + 1e-12f) - 0.01f);
        } else { v = vn; s = sn; in_ = in_ + wA[j]; }
      } else { v = vn; s = sn; }
      ci = in_;
      float* yo = ys + ((size_t)t * NN + n) * 3;
      yo[0] = v; yo[1] = ci; yo[2] = s;
    }
#pragma unroll
    for (int j = 0; j < CH; ++j) { inA[j]=inB[j]; lrA[j]=lrB[j]; wA[j]=wB[j]; }
  }
}

// ---------------- Phase B: decoupled closed-form tail (1 thr/neuron) -------
__global__ __launch_bounds__(TPB) void p1_segc(
    const float* __restrict__ ts, const float* __restrict__ inp,
    const float* __restrict__ mu, const float* __restrict__ ys,
    const unsigned int* __restrict__ hdr, float* __restrict__ buf1)
{
  const unsigned int Kp = hdr[0];
  const unsigned int g0 = Kp / LSEG;
  const unsigned int g = blockIdx.x >> 4;
  if (g < g0) return;
  const int n = (int)(blockIdx.x & 15) * TPB + threadIdx.x;
  const float dt = ts[1] - ts[0];
  const float mu1 = mu[0], mu2 = mu[1];
  const float a = 1.0f - dt * mu1, b = dt * mu1, r = 1.0f - dt * mu2;
  const float ibase = ys[((size_t)(Kp - 1) * NN + n) * 3 + 1];
  float ij = ibase * powf(r, (float)((int)(g * LSEG) - (int)Kp));
  float c = 0.0f;
  const float* p = inp + (size_t)g * LSEG * NN + n;
#pragma unroll 8
  for (int j = 0; j < LSEG; ++j) {
    float x = *p; p += NN;
    c = a * c + b * (ij + x);
    ij *= r;
  }
  buf1[(size_t)g * NN + n] = c;
}

__global__ __launch_bounds__(TPB) void p2_scanv(
    const float* __restrict__ ts, const float* __restrict__ mu,
    const float* __restrict__ ys, const unsigned int* __restrict__ hdr,
    float* __restrict__ buf1)
{
  const unsigned int Kp = hdr[0];
  const unsigned int g0 = Kp / LSEG;
  if (g0 >= NSEG) return;
  const int n = blockIdx.x * TPB + threadIdx.x;
  const float dt = ts[1] - ts[0];
  const float a = 1.0f - dt * mu[0];
  float aL = a;
  for (int k = 0; k < 6; ++k) aL *= aL;   // a^64
  float v = ys[((size_t)(Kp - 1) * NN + n) * 3];
  for (unsigned int g = g0; g < NSEG; ++g) {
    float cg = buf1[(size_t)g * NN + n];
    buf1[(size_t)g * NN + n] = v;
    v = aL * v + cg;
  }
}

__global__ __launch_bounds__(TPB) void p3a_sigma(
    const float* __restrict__ ts, const float* __restrict__ inp,
    const float* __restrict__ mu, const unsigned int* __restrict__ hdr,
    const float* __restrict__ buf1, const float* __restrict__ ys,
    float* __restrict__ buf2)
{
  const unsigned int Kp = hdr[0];
  const unsigned int g0 = Kp / LSEG;
  const unsigned int g = blockIdx.x >> 4;
  if (g < g0) return;
  const int n = (int)(blockIdx.x & 15) * TPB + threadIdx.x;
  const float dt = ts[1] - ts[0];
  const float mu1 = mu[0], mu2 = mu[1];
  const float r = 1.0f - dt * mu2;
  float v = buf1[(size_t)g * NN + n];
  const float ibase = ys[((size_t)(Kp - 1) * NN + n) * 3 + 1];
  float i = ibase * powf(r, (float)((int)(g * LSEG) - (int)Kp));
  float sl = 0.0f;
  const float* p = inp + (size_t)g * LSEG * NN + n;
#pragma unroll 8
  for (int j = 0; j < LSEG; ++j) {
    float x = *p; p += NN;
    float sig = 1.0f / (1.0f + expf(-v));
    sl = sl + dt * sig;
    float vn = v + dt * (mu1 * (i - v) + mu1 * x);
    float in_ = i + dt * (-mu2 * i);
    v = vn; i = in_;
  }
  buf2[(size_t)g * NN + n] = sl;
}

__global__ __launch_bounds__(TPB) void p4_scans(
    const float* __restrict__ ys, const unsigned int* __restrict__ hdr,
    float* __restrict__ buf2)
{
  const unsigned int Kp = hdr[0];
  const unsigned int g0 = Kp / LSEG;
  if (g0 >= NSEG) return;
  const int n = blockIdx.x * TPB + threadIdx.x;
  float s = ys[((size_t)(Kp - 1) * NN + n) * 3 + 2];
  for (unsigned int g = g0; g < NSEG; ++g) {
    float t = buf2[(size_t)g * NN + n];
    buf2[(size_t)g * NN + n] = s;
    s += t;
  }
}

__global__ __launch_bounds__(TPB) void p3b_write(
    const float* __restrict__ ts, const float* __restrict__ inp,
    const float* __restrict__ mu, const unsigned int* __restrict__ hdr,
    const float* __restrict__ buf1, const float* __restrict__ buf2,
    float* __restrict__ ys)
{
  const unsigned int Kp = hdr[0];
  const unsigned int g0 = Kp / LSEG;
  const unsigned int g = blockIdx.x >> 4;
  if (g < g0) return;
  const int n = (int)(blockIdx.x & 15) * TPB + threadIdx.x;
  const float dt = ts[1] - ts[0];
  const float mu1 = mu[0], mu2 = mu[1];
  const float r = 1.0f - dt * mu2;
  float v = buf1[(size_t)g * NN + n];
  float s = buf2[(size_t)g * NN + n];
  const float ibase = ys[((size_t)(Kp - 1) * NN + n) * 3 + 1];
  float i = ibase * powf(r, (float)((int)(g * LSEG) - (int)Kp));
  const float* p = inp + (size_t)g * LSEG * NN + n;
  float* yo = ys + ((size_t)g * LSEG * NN + n) * 3;
#pragma unroll 4
  for (int j = 0; j < LSEG; ++j) {
    float x = *p; p += NN;
    float sig = 1.0f / (1.0f + expf(-v));
    s = s + dt * sig;
    float vn = v + dt * (mu1 * (i - v) + mu1 * x);
    float in_ = i + dt * (-mu2 * i);
    yo[0] = vn; yo[1] = in_; yo[2] = s;
    yo += (size_t)NN * 3;
    v = vn; i = in_;
  }
}

extern "C" void kernel_launch(void* const* d_in, const int* in_sizes, int n_in,
                              void* d_out, int out_size, void* d_ws, size_t ws_size,
                              hipStream_t stream)
{
  (void)in_sizes; (void)n_in; (void)out_size; (void)ws_size;
  const float* ts  = (const float*)d_in[0];
  const float* inp = (const float*)d_in[1];
  const float* w   = (const float*)d_in[2];
  const float* v0  = (const float*)d_in[3];
  const float* i0  = (const float*)d_in[4];
  const float* mu  = (const float*)d_in[5];
  const float* s0u = (const float*)d_in[6];
  const float* ru  = (const float*)d_in[7];
  const int*   mx  = (const int*)d_in[8];
  float* ys = (float*)d_out;

  char* wsb = (char*)d_ws;
  unsigned int* hdr   = (unsigned int*)wsb;               // 64 B
  unsigned int* trace = (unsigned int*)(wsb + 1024);      // TT*4 = 8 KB
  float* buf1 = (float*)(wsb + 1024 + TT * 4);            // 512 KB
  float* buf2 = buf1 + (size_t)NSEG * NN;                 // 512 KB

  // log-table in the TAIL of ys (last LRROWS*NN floats = 4 MB): consumed by
  // phaseA + replay, and only overwritten later by p3b (rows >= K').
  float* lr = ys + (size_t)TT * NN * 3 - (size_t)LRROWS * NN;

  plog_k<<<LRROWS * NN / 4 / TPB, TPB, 0, stream>>>(ru, lr);
  phaseA<<<1, ATPB, 0, stream>>>(ts, inp, w, v0, i0, mu, s0u, ru, lr, mx, trace, hdr);
  replay_k<<<NN / RTPB, RTPB, 0, stream>>>(ts, inp, w, v0, i0, mu, s0u, ru, lr,
                                           trace, hdr, ys);
  p1_segc<<<NSEG * 16, TPB, 0, stream>>>(ts, inp, mu, ys, hdr, buf1);
  p2_scanv<<<NN / TPB, TPB, 0, stream>>>(ts, mu, ys, hdr, buf1);
  p3a_sigma<<<NSEG * 16, TPB, 0, stream>>>(ts, inp, mu, hdr, buf1, ys, buf2);
  p4_scans<<<NN / TPB, TPB, 0, stream>>>(ys, hdr, buf2);
  p3b_write<<<NSEG * 16, TPB, 0, stream>>>(ts, inp, mu, hdr, buf1, buf2, ys);
}